// Round 1
// baseline (136.325 us; speedup 1.0000x reference)
//
#include <hip/hip_runtime.h>
#include <math.h>

#define NSRC 1000
#define NTGT 100
#define NCLS 256
#define NB   32
#define NSP  1024                 // padded column count for LSA
#define CHUNK 64                  // source rows per cost block
#define NCHK  16                  // chunks per batch (16*64 = 1024 = NSP)
#define CEP   101                 // ce_lds pitch: gcd(101,32)=1 -> conflict-free
#define PAD_IDX(j) ((j) + ((j) >> 4))
#define LDSN (NSP + (NSP >> 4))   // 1088 padded LDS entries
#define AUCTION_EPS 0.04f
#define NWAVES 8
#define ROUND_CAP 96

// R6 post-mortem: column reduction (v[j]=colmin>0) is INVALID for rectangular
// LAP (dual needs v<=0, v<0 only on matched cols). v starts 0, only decreases.
// R7 post-mortem: harness poison-fill of d_ws (256 MiB @ 6.2 TB/s = 43.5 us)
// plus input restore/gaps is a fixed ~100 us floor. Controllable: lse+cost+lsa.
// R8 post-mortem: lsa ~= 28 us; eps=0.01 price wars + Dijkstra row-load latency
// are the two remaining serial terms.
// R9 theory: logits (32 MB) crossed HBM twice (lse stream + CE gather). Fuse
// LSE into cost: per-row butterfly reduce while row is in registers, extract
// the 100 picked logits via 4 __shfl per 64-target group, ce staged in LDS.
// Row top-2 becomes per-chunk partials merged exactly in lsa init.

// ---- fused: logsumexp + CE pick + giou cost + partial top-2 ----------------
// grid = NB * NCHK blocks; b = blockIdx&31, chunk = blockIdx>>5.
__global__ __launch_bounds__(256) void cost_kernel(const float* __restrict__ logits,
                                                   const int*   __restrict__ tcls,
                                                   const float* __restrict__ sbox,
                                                   const float* __restrict__ tbox,
                                                   float*       __restrict__ cost,
                                                   float*       __restrict__ pm1,
                                                   float*       __restrict__ pm2,
                                                   int*         __restrict__ pmi) {
    int b     = blockIdx.x & 31;
    int chunk = blockIdx.x >> 5;
    int s0    = chunk * CHUNK;
    int wid   = threadIdx.x >> 6;
    int lane  = threadIdx.x & 63;

    __shared__ float  ce_lds[CHUNK][CEP];   // ce[s_local][t]
    __shared__ float4 sb_lds[CHUNK];
    __shared__ float4 tb_lds[NTGT];
    __shared__ int    cls_lds[128];

    for (int t = threadIdx.x; t < NTGT; t += 256) {
        tb_lds[t]  = reinterpret_cast<const float4*>(tbox)[b * NTGT + t];
        cls_lds[t] = tcls[b * NTGT + t];
    }
    if (threadIdx.x < 128 - NTGT) cls_lds[NTGT + threadIdx.x] = 0;
    int valid = NSRC - s0; valid = valid > CHUNK ? CHUNK : valid;   // 64 or 40
    for (int r = threadIdx.x; r < valid; r += 256)
        sb_lds[r] = reinterpret_cast<const float4*>(sbox)[b * NSRC + s0 + r];
    __syncthreads();

    // ---- phase 1: per-wave rows (interleaved). lse + picked-logit extraction.
    // Arithmetic identical to the old lse_kernel (same reduce order) so the
    // downstream values stay bit-exact.
    #pragma unroll 2
    for (int r = wid; r < valid; r += 4) {
        int gs = b * NSRC + s0 + r;
        float4 v4 = reinterpret_cast<const float4*>(logits + (size_t)gs * NCLS)[lane];
        float m = fmaxf(fmaxf(v4.x, v4.y), fmaxf(v4.z, v4.w));
        #pragma unroll
        for (int off = 32; off >= 1; off >>= 1) m = fmaxf(m, __shfl_xor(m, off));
        float s = expf(v4.x - m) + expf(v4.y - m) + expf(v4.z - m) + expf(v4.w - m);
        #pragma unroll
        for (int off = 32; off >= 1; off >>= 1) s += __shfl_xor(s, off);
        float lse = m + logf(s);
        // pick group 0: targets t = lane (0..63)
        int c0 = cls_lds[lane];
        int l0 = c0 >> 2, e0 = c0 & 3;
        float px = __shfl(v4.x, l0), py = __shfl(v4.y, l0),
              pz = __shfl(v4.z, l0), pw = __shfl(v4.w, l0);
        float p0 = e0 == 0 ? px : e0 == 1 ? py : e0 == 2 ? pz : pw;
        ce_lds[r][lane] = lse - p0;
        // pick group 1: targets t = 64+lane (lane < 36)
        int c1 = cls_lds[64 + lane];
        int l1s = c1 >> 2, e1 = c1 & 3;
        float qx = __shfl(v4.x, l1s), qy = __shfl(v4.y, l1s),
              qz = __shfl(v4.z, l1s), qw = __shfl(v4.w, l1s);
        float p1 = e1 == 0 ? qx : e1 == 1 ? qy : e1 == 2 ? qz : qw;
        if (lane < NTGT - 64) ce_lds[r][64 + lane] = lse - p1;
    }
    __syncthreads();

    // ---- phase 2: giou/l1 cost, coalesced writes, per-chunk top-2 partials
    bool vs = lane < valid;
    float4 sb = sb_lds[vs ? lane : 0];
    float area_s = (sb.z - sb.x) * (sb.w - sb.y);
    int sg = s0 + lane;
    for (int t = wid; t < NTGT; t += 4) {
        float4 tb = tb_lds[t];
        float area_t = (tb.z - tb.x) * (tb.w - tb.y);
        float c = 1e30f;
        if (vs) {
            float ce = ce_lds[lane][t];
            float ix1 = fmaxf(sb.x, tb.x), iy1 = fmaxf(sb.y, tb.y);
            float ix2 = fminf(sb.z, tb.z), iy2 = fminf(sb.w, tb.w);
            float inter = fmaxf(ix2 - ix1, 0.f) * fmaxf(iy2 - iy1, 0.f);
            float uni = area_s + area_t - inter;
            float iou = inter / uni;
            float cx1 = fminf(sb.x, tb.x), cy1 = fminf(sb.y, tb.y);
            float cx2 = fmaxf(sb.z, tb.z), cy2 = fmaxf(sb.w, tb.w);
            float carea = (cx2 - cx1) * (cy2 - cy1);
            float giou = iou - (carea - uni) / carea;
            float l1 = 0.25f * (fabsf(sb.x - tb.x) + fabsf(sb.y - tb.y) +
                                fabsf(sb.z - tb.z) + fabsf(sb.w - tb.w));
            c = ce + 10.0f * (1.0f - giou) + l1;
        }
        cost[(size_t)(b * NTGT + t) * NSP + sg] = c;
        // top-2 with index over this chunk (pads excluded, same as before)
        float m1 = vs ? c : 1e38f, m2 = 1e38f;
        int   mi = vs ? sg : 0x7fffffff;
        #pragma unroll
        for (int off = 32; off >= 1; off >>= 1) {
            float om1 = __shfl_xor(m1, off);
            float om2 = __shfl_xor(m2, off);
            int   oi  = __shfl_xor(mi, off);
            bool take = (om1 < m1) || (om1 == m1 && oi < mi);
            float lose = take ? m1 : om1;
            m1 = take ? om1 : m1;
            mi = take ? oi  : mi;
            m2 = fminf(fminf(m2, om2), lose);
        }
        if (lane == 0) {
            int idx = (b * NTGT + t) * NCHK + chunk;
            pm1[idx] = m1; pm2[idx] = m2; pmi[idx] = mi;
        }
    }
}

// ---------------- JV: claim -> eps-auction with bid repair -> Dijkstra ------
// One block (512 threads = 8 waves) per batch. Phase C uses an index-carrying
// top-2 butterfly and speculative prefetch of the runner-up column's owner row
// (pcol is immutable during one Dijkstra, so the prefetch is always coherent).
__global__ __launch_bounds__(512) void lsa_kernel(const float* __restrict__ cost,
                                                  const float* __restrict__ pm1,
                                                  const float* __restrict__ pm2,
                                                  const int*   __restrict__ pmi,
                                                  float* __restrict__ out) {
    int b    = blockIdx.x;
    int tid  = threadIdx.x;
    int wv   = tid >> 6;
    int lane = tid & 63;
    const float* C = cost + (size_t)b * NTGT * NSP;
    __shared__ int   way[LDSN];     // pred chain; reused as claim[] first
    __shared__ int   pcol[LDSN];    // col -> assigned row
    __shared__ float uu[LDSN];      // col -> u of its assigned row
    __shared__ float vsh[LDSN];     // column duals v (<= 0)
    __shared__ float urow[NTGT];    // row dual u
    __shared__ int   done[NTGT];    // currently assigned?
    __shared__ float bm1[NTGT];     // stored bid: best reduced cost at scan
    __shared__ float bm2[NTGT];     //             second-best (lower bound)
    __shared__ int   bj [NTGT];     //             best column
    __shared__ float bv [NTGT];     //             v[bj] at scan time
    __shared__ int   qbuf[1024];    // ring buffer of free rows
    __shared__ int   qstate[2];     // qh, qt
    __shared__ int   srow[NWAVES];

    for (int t = tid; t < LDSN; t += 512) {
        pcol[t] = -1; uu[t] = 0.f; vsh[t] = 0.f; way[t] = 0x7fffffff;
    }
    // exact top-2 merge of the 16 per-chunk partials (same tie-break order)
    for (int t = tid; t < NTGT; t += 512) {
        int base16 = (b * NTGT + t) * NCHK;
        float m1 = pm1[base16], m2 = pm2[base16];
        int   mi = pmi[base16];
        #pragma unroll
        for (int k = 1; k < NCHK; ++k) {
            float om1 = pm1[base16 + k], om2 = pm2[base16 + k];
            int   oi  = pmi[base16 + k];
            bool take = (om1 < m1) || (om1 == m1 && oi < mi);
            float lose = take ? m1 : om1;
            m1 = take ? om1 : m1;
            mi = take ? oi  : mi;
            m2 = fminf(fminf(m2, om2), lose);
        }
        urow[t] = m1;
        bm1[t]  = m1;
        bm2[t]  = m2;
        bj[t]   = mi;
        bv[t]   = 0.f;
    }
    if (tid == 0) { qstate[0] = 0; qstate[1] = 0; }
    __syncthreads();

    // ---- Phase A: claim argmin columns (lowest row index wins)
    for (int r = tid; r < NTGT; r += 512) atomicMin(&way[PAD_IDX(bj[r])], r);
    __syncthreads();
    for (int r = tid; r < NTGT; r += 512) {
        int j = bj[r];
        int w = (way[PAD_IDX(j)] == r) ? 1 : 0;
        done[r] = w;
        if (w) { pcol[PAD_IDX(j)] = r; uu[PAD_IDX(j)] = urow[r]; }
    }
    __syncthreads();

    // ---- queue build: wave 0 ballot compaction of Phase-A losers
    if (tid < 64) {
        int qt = 0;
        #pragma unroll
        for (int r0 = 0; r0 < 128; r0 += 64) {
            int r = r0 + lane;
            bool act = (r < NTGT) && !done[r];
            unsigned long long mask = __ballot(act);
            if (act) qbuf[qt + __popcll(mask & ((1ull << lane) - 1ull))] = r;
            qt += __popcll(mask);
        }
        if (lane == 0) qstate[1] = qt;
    }
    __syncthreads();

    int base = lane * 16;

    // ---- Phase B: rounds of (repair-check / rescan) + serial commit
    for (int round = 0; round < ROUND_CAP; ++round) {
        int qh = qstate[0], qt = qstate[1];   // uniform after barrier
        int navail = qt - qh;
        if (navail <= 0) break;
        int take = navail < NWAVES ? navail : NWAVES;
        if (wv < take) {
            int i = qbuf[(qh + wv) & 1023];   // wave-uniform
            if (lane == 0) srow[wv] = i;
            // repairable? exact current reduced cost at stored best column
            float m1p = bm1[i] + (bv[i] - vsh[PAD_IDX(bj[i])]);
            if (m1p > bm2[i]) {
                // full rescan against current prices; store fresh bid
                const float4* row4 = reinterpret_cast<const float4*>(C + (size_t)i * NSP + base);
                float m1 = 1e38f, m2 = 1e38f; int j1 = 0x7fffffff;
                #pragma unroll
                for (int q = 0; q < 4; ++q) {
                    float4 c4 = row4[q];
                    float vals[4];
                    vals[0] = c4.x - vsh[PAD_IDX(base + 4*q + 0)];
                    vals[1] = c4.y - vsh[PAD_IDX(base + 4*q + 1)];
                    vals[2] = c4.z - vsh[PAD_IDX(base + 4*q + 2)];
                    vals[3] = c4.w - vsh[PAD_IDX(base + 4*q + 3)];
                    #pragma unroll
                    for (int e = 0; e < 4; ++e) {
                        float val = vals[e];
                        if (val < m1) { m2 = m1; m1 = val; j1 = base + 4*q + e; }
                        else m2 = fminf(m2, val);
                    }
                }
                #pragma unroll
                for (int off = 32; off >= 1; off >>= 1) {
                    float om1 = __shfl_xor(m1, off);
                    float om2 = __shfl_xor(m2, off);
                    int   oj1 = __shfl_xor(j1, off);
                    bool tk = (om1 < m1) || (om1 == m1 && oj1 < j1);
                    float lose = tk ? m1 : om1;
                    m1 = tk ? om1 : m1;
                    j1 = tk ? oj1 : j1;
                    m2 = fminf(fminf(m2, om2), lose);
                }
                if (lane == 0) {
                    bm1[i] = m1; bm2[i] = m2; bj[i] = j1;
                    bv[i]  = vsh[PAD_IDX(j1)];
                }
            }
        }
        __syncthreads();
        if (tid == 0) {
            int qt2 = qstate[1];
            for (int s = 0; s < take; ++s) {
                int i  = srow[s];
                int j1 = bj[i];
                int pj1 = PAD_IDX(j1);
                float vnow = vsh[pj1];
                float m1p  = bm1[i] + (bv[i] - vnow);   // exact current rc at j1
                if (m1p <= bm2[i]) {
                    float delta = fmaxf(bm2[i] - m1p, AUCTION_EPS);
                    int old = pcol[pj1];
                    vsh[pj1]  = vnow - delta;
                    pcol[pj1] = i;
                    uu[pj1]   = m1p + delta;            // matched edge tight
                    urow[i]   = m1p + delta;
                    done[i]   = 1;
                    if (old >= 0) { qbuf[qt2 & 1023] = old; ++qt2; done[old] = 0; }
                } else {
                    qbuf[qt2 & 1023] = i; ++qt2;        // rescan next round
                }
            }
            qstate[0] = qstate[0] + take;
            qstate[1] = qt2;
        }
        __syncthreads();
    }

    // ---- Phase C: exact shortest augmenting path for leftovers (wave 0)
    float v[16], d[16];
    if (tid < 64) {
        #pragma unroll
        for (int k = 0; k < 16; ++k) v[k] = vsh[PAD_IDX(base + k)];
    }
    __syncthreads();

    for (int i = 0; i < NTGT; ++i) {
        if (done[i]) continue;                 // uniform LDS read
        float ui = urow[i];
        float Df = 0.f;
        int jf = -1;
        if (tid < 64) {
            const float4* row4 = reinterpret_cast<const float4*>(C + (size_t)i * NSP + base);
            #pragma unroll
            for (int q = 0; q < 4; ++q) {
                float4 c4 = row4[q];
                d[4*q+0] = c4.x - ui - v[4*q+0];
                d[4*q+1] = c4.y - ui - v[4*q+1];
                d[4*q+2] = c4.z - ui - v[4*q+2];
                d[4*q+3] = c4.w - ui - v[4*q+3];
            }
            #pragma unroll
            for (int k = 0; k < 16; ++k) way[PAD_IDX(base + k)] = -1;
            unsigned int used = 0;
            int   pf_j = -1;                    // prefetched column (owner row data)
            float pfr[16];

            for (int it = 0; it < NTGT + 3; ++it) {
                // per-lane top-2 (value,index)
                float l1 = 1e38f, l2 = 1e38f;
                int   i1 = 0x7fffffff, i2 = 0x7fffffff;
                #pragma unroll
                for (int k = 0; k < 16; ++k) {
                    float val = ((used >> k) & 1u) ? 1e38f : d[k];
                    int idx = base + k;
                    if (val < l1) { l2 = l1; i2 = i1; l1 = val; i1 = idx; }
                    else if (val < l2) { l2 = val; i2 = idx; }
                }
                // index-carrying top-2 butterfly (no ballot needed)
                #pragma unroll
                for (int off = 32; off >= 1; off >>= 1) {
                    float ob1 = __shfl_xor(l1, off), ob2 = __shfl_xor(l2, off);
                    int   oc1 = __shfl_xor(i1, off), oc2 = __shfl_xor(i2, off);
                    bool tk = (ob1 < l1) || (ob1 == l1 && oc1 < i1);
                    float n1 = tk ? ob1 : l1; int ni1 = tk ? oc1 : i1;
                    float lz = tk ? l1  : ob1; int liz = tk ? i1  : oc1; // loser
                    float n2 = lz; int ni2 = liz;
                    if (l2  < n2) { n2 = l2;  ni2 = i2;  }
                    if (ob2 < n2) { n2 = ob2; ni2 = oc2; }
                    l1 = n1; i1 = ni1; l2 = n2; i2 = ni2;
                }
                float wmin = l1; int j0 = i1; int j0b = i2;
                if (wmin >= 1e37f) break;             // safety net
                int pj0 = pcol[PAD_IDX(j0)];
                if (pj0 < 0) { Df = wmin; jf = j0; break; }   // free column
                if ((j0 >> 4) == lane) used |= 1u << (j0 & 15);
                float uref = uu[PAD_IDX(j0)];
                float sft  = wmin - uref;
                // obtain row pj0 (reuse prefetch on hit)
                float cr[16];
                if (pf_j == j0) {
                    #pragma unroll
                    for (int k = 0; k < 16; ++k) cr[k] = pfr[k];
                    pf_j = -1;
                } else {
                    const float4* rr = reinterpret_cast<const float4*>(C + (size_t)pj0 * NSP + base);
                    #pragma unroll
                    for (int q = 0; q < 4; ++q) {
                        float4 c4 = rr[q];
                        cr[4*q+0] = c4.x; cr[4*q+1] = c4.y; cr[4*q+2] = c4.z; cr[4*q+3] = c4.w;
                    }
                }
                // speculative prefetch: runner-up column's owner row
                if (j0b < NSP && j0b != pf_j) {
                    int pj0b = pcol[PAD_IDX(j0b)];
                    if (pj0b >= 0) {
                        const float4* rb = reinterpret_cast<const float4*>(C + (size_t)pj0b * NSP + base);
                        #pragma unroll
                        for (int q = 0; q < 4; ++q) {
                            float4 c4 = rb[q];
                            pfr[4*q+0] = c4.x; pfr[4*q+1] = c4.y;
                            pfr[4*q+2] = c4.z; pfr[4*q+3] = c4.w;
                        }
                        pf_j = j0b;
                    } else pf_j = -1;
                }
                // relax
                #pragma unroll
                for (int k = 0; k < 16; ++k) {
                    float cand = sft + cr[k] - v[k];
                    bool upd = (cand < d[k]) && !((used >> k) & 1u);
                    if (upd) { d[k] = cand; way[PAD_IDX(base + k)] = j0; }
                }
            }

            // dual updates: v -= (Df - d), u[row] += (Df - d) on scanned cols
            if (jf >= 0) {
                #pragma unroll
                for (int k = 0; k < 16; ++k) {
                    if ((used >> k) & 1u) {
                        float diff = Df - d[k];
                        v[k] -= diff;
                        uu[PAD_IDX(base + k)] += diff;
                    }
                }
            }
        }
        __syncthreads();
        if (tid == 0 && jf >= 0) {            // tid 0 is lane 0 of wave 0
            int j = jf;
            for (int g = 0; g < NSP; ++g) {
                int jp = way[PAD_IDX(j)];
                if (jp < 0) { pcol[PAD_IDX(j)] = i; uu[PAD_IDX(j)] = ui + Df; break; }
                pcol[PAD_IDX(j)] = pcol[PAD_IDX(jp)];
                uu[PAD_IDX(j)]   = uu[PAD_IDX(jp)];
                j = jp;
            }
            done[i] = 1;
        }
        __syncthreads();
    }

    // ---- mean of matched costs (wave 0)
    if (tid < 64) {
        float acc = 0.f;
        #pragma unroll
        for (int k = 0; k < 16; ++k) {
            int j = base + k;
            if (j < NSRC) {
                int r = pcol[PAD_IDX(j)];
                if (r >= 0) acc += C[(size_t)r * NSP + j];
            }
        }
        #pragma unroll
        for (int off = 32; off >= 1; off >>= 1) acc += __shfl_xor(acc, off);
        if (lane == 0) out[b] = acc * (1.0f / NTGT);
    }
}

extern "C" void kernel_launch(void* const* d_in, const int* in_sizes, int n_in,
                              void* d_out, int out_size, void* d_ws, size_t ws_size,
                              hipStream_t stream) {
    const float* logits = (const float*)d_in[0];   // (32,1000,256) f32
    const int*   tcls   = (const int*)  d_in[1];   // (32,100) i32
    const float* sbox   = (const float*)d_in[2];   // (32,1000,4) f32
    const float* tbox   = (const float*)d_in[3];   // (32,100,4) f32
    float* out = (float*)d_out;                    // (32,) f32

    float* cost = (float*)d_ws;                            // 32*100*1024 floats (~13.1 MB)
    float* pm1  = cost + (size_t)NB * NTGT * NSP;          // 3200*16 floats
    float* pm2  = pm1 + (size_t)NB * NTGT * NCHK;          // 3200*16 floats
    int*   pmi  = (int*)(pm2 + (size_t)NB * NTGT * NCHK);  // 3200*16 ints

    cost_kernel<<<NB * NCHK, 256, 0, stream>>>(logits, tcls, sbox, tbox, cost,
                                               pm1, pm2, pmi);
    lsa_kernel <<<NB,        512, 0, stream>>>(cost, pm1, pm2, pmi, out);
}

// Round 2
// 124.374 us; speedup vs baseline: 1.0961x; 1.0961x over previous
//
#include <hip/hip_runtime.h>
#include <math.h>

#define NSRC 1000
#define NTGT 100
#define NCLS 256
#define NB   32
#define NSP  1024                 // padded column count for LSA
#define CHUNK 64                  // source rows per cost block
#define NCHK  16                  // chunks per batch (16*64 = 1024 = NSP)
#define CEP   101                 // ce_lds pitch: gcd(101,32)=1 -> conflict-free
#define PAD_IDX(j) ((j) + ((j) >> 4))
#define LDSN (NSP + (NSP >> 4))   // 1088 padded LDS entries
#define AUCTION_EPS 0.04f
#define NWAVES 8
#define ROUND_CAP 96

// R6 post-mortem: column reduction (v[j]=colmin>0) is INVALID for rectangular
// LAP (dual needs v<=0, v<0 only on matched cols). v starts 0, only decreases.
// R7 post-mortem: harness poison-fill of d_ws (256 MiB @ 6.2 TB/s = 43.5 us)
// plus input restore/gaps is a fixed ~100 us floor. Controllable: lse+cost+lsa.
// R8 post-mortem: lsa ~= 28 us; eps=0.01 price wars + Dijkstra row-load latency
// are the two remaining serial terms.
// R9 post-mortem: fusion halved HBM traffic (FETCH 16 MB) but kernel went
// latency-bound: 2048 waves total (8/CU) and 16 serial rows/wave with a
// ~2.5K-cycle dependent chain each => 45 us, VALUBusy 31%, hbm 8%.
// R10: same fusion, 512-thread blocks (8 waves). 16 waves/CU (old lse's
// occupancy), 8 rows/wave phase 1, 64-lane phase 2 at t+=8. Bit-identical
// arithmetic; pure latency-hiding restructure.

// ---- fused: logsumexp + CE pick + giou cost + partial top-2 ----------------
// grid = NB * NCHK blocks; b = blockIdx&31, chunk = blockIdx>>5.
__global__ __launch_bounds__(512) void cost_kernel(const float* __restrict__ logits,
                                                   const int*   __restrict__ tcls,
                                                   const float* __restrict__ sbox,
                                                   const float* __restrict__ tbox,
                                                   float*       __restrict__ cost,
                                                   float*       __restrict__ pm1,
                                                   float*       __restrict__ pm2,
                                                   int*         __restrict__ pmi) {
    int b     = blockIdx.x & 31;
    int chunk = blockIdx.x >> 5;
    int s0    = chunk * CHUNK;
    int wid   = threadIdx.x >> 6;   // 0..7
    int lane  = threadIdx.x & 63;

    __shared__ float  ce_lds[CHUNK][CEP];   // ce[s_local][t]
    __shared__ float4 sb_lds[CHUNK];
    __shared__ float4 tb_lds[NTGT];
    __shared__ int    cls_lds[128];

    for (int t = threadIdx.x; t < NTGT; t += 512) {
        tb_lds[t]  = reinterpret_cast<const float4*>(tbox)[b * NTGT + t];
        cls_lds[t] = tcls[b * NTGT + t];
    }
    if (threadIdx.x < 128 - NTGT) cls_lds[NTGT + threadIdx.x] = 0;
    int valid = NSRC - s0; valid = valid > CHUNK ? CHUNK : valid;   // 64 or 40
    for (int r = threadIdx.x; r < valid; r += 512)
        sb_lds[r] = reinterpret_cast<const float4*>(sbox)[b * NSRC + s0 + r];
    __syncthreads();

    // ---- phase 1: per-wave rows (interleaved). lse + picked-logit extraction.
    // Arithmetic identical to the original lse_kernel (same reduce order) so
    // downstream values stay bit-exact. 8 rows/wave, unroll-2 ILP.
    #pragma unroll 2
    for (int r = wid; r < valid; r += 8) {
        int gs = b * NSRC + s0 + r;
        float4 v4 = reinterpret_cast<const float4*>(logits + (size_t)gs * NCLS)[lane];
        float m = fmaxf(fmaxf(v4.x, v4.y), fmaxf(v4.z, v4.w));
        #pragma unroll
        for (int off = 32; off >= 1; off >>= 1) m = fmaxf(m, __shfl_xor(m, off));
        float s = expf(v4.x - m) + expf(v4.y - m) + expf(v4.z - m) + expf(v4.w - m);
        #pragma unroll
        for (int off = 32; off >= 1; off >>= 1) s += __shfl_xor(s, off);
        float lse = m + logf(s);
        // pick group 0: targets t = lane (0..63)
        int c0 = cls_lds[lane];
        int l0 = c0 >> 2, e0 = c0 & 3;
        float px = __shfl(v4.x, l0), py = __shfl(v4.y, l0),
              pz = __shfl(v4.z, l0), pw = __shfl(v4.w, l0);
        float p0 = e0 == 0 ? px : e0 == 1 ? py : e0 == 2 ? pz : pw;
        ce_lds[r][lane] = lse - p0;
        // pick group 1: targets t = 64+lane (lane < 36)
        int c1 = cls_lds[64 + lane];
        int l1s = c1 >> 2, e1 = c1 & 3;
        float qx = __shfl(v4.x, l1s), qy = __shfl(v4.y, l1s),
              qz = __shfl(v4.z, l1s), qw = __shfl(v4.w, l1s);
        float p1 = e1 == 0 ? qx : e1 == 1 ? qy : e1 == 2 ? qz : qw;
        if (lane < NTGT - 64) ce_lds[r][64 + lane] = lse - p1;
    }
    __syncthreads();

    // ---- phase 2: giou/l1 cost, coalesced writes, per-chunk top-2 partials
    bool vs = lane < valid;
    float4 sb = sb_lds[vs ? lane : 0];
    float area_s = (sb.z - sb.x) * (sb.w - sb.y);
    int sg = s0 + lane;
    for (int t = wid; t < NTGT; t += 8) {
        float4 tb = tb_lds[t];
        float area_t = (tb.z - tb.x) * (tb.w - tb.y);
        float c = 1e30f;
        if (vs) {
            float ce = ce_lds[lane][t];
            float ix1 = fmaxf(sb.x, tb.x), iy1 = fmaxf(sb.y, tb.y);
            float ix2 = fminf(sb.z, tb.z), iy2 = fminf(sb.w, tb.w);
            float inter = fmaxf(ix2 - ix1, 0.f) * fmaxf(iy2 - iy1, 0.f);
            float uni = area_s + area_t - inter;
            float iou = inter / uni;
            float cx1 = fminf(sb.x, tb.x), cy1 = fminf(sb.y, tb.y);
            float cx2 = fmaxf(sb.z, tb.z), cy2 = fmaxf(sb.w, tb.w);
            float carea = (cx2 - cx1) * (cy2 - cy1);
            float giou = iou - (carea - uni) / carea;
            float l1 = 0.25f * (fabsf(sb.x - tb.x) + fabsf(sb.y - tb.y) +
                                fabsf(sb.z - tb.z) + fabsf(sb.w - tb.w));
            c = ce + 10.0f * (1.0f - giou) + l1;
        }
        cost[(size_t)(b * NTGT + t) * NSP + sg] = c;
        // top-2 with index over this chunk (pads excluded, same as before)
        float m1 = vs ? c : 1e38f, m2 = 1e38f;
        int   mi = vs ? sg : 0x7fffffff;
        #pragma unroll
        for (int off = 32; off >= 1; off >>= 1) {
            float om1 = __shfl_xor(m1, off);
            float om2 = __shfl_xor(m2, off);
            int   oi  = __shfl_xor(mi, off);
            bool take = (om1 < m1) || (om1 == m1 && oi < mi);
            float lose = take ? m1 : om1;
            m1 = take ? om1 : m1;
            mi = take ? oi  : mi;
            m2 = fminf(fminf(m2, om2), lose);
        }
        if (lane == 0) {
            int idx = (b * NTGT + t) * NCHK + chunk;
            pm1[idx] = m1; pm2[idx] = m2; pmi[idx] = mi;
        }
    }
}

// ---------------- JV: claim -> eps-auction with bid repair -> Dijkstra ------
// One block (512 threads = 8 waves) per batch. Phase C uses an index-carrying
// top-2 butterfly and speculative prefetch of the runner-up column's owner row
// (pcol is immutable during one Dijkstra, so the prefetch is always coherent).
__global__ __launch_bounds__(512) void lsa_kernel(const float* __restrict__ cost,
                                                  const float* __restrict__ pm1,
                                                  const float* __restrict__ pm2,
                                                  const int*   __restrict__ pmi,
                                                  float* __restrict__ out) {
    int b    = blockIdx.x;
    int tid  = threadIdx.x;
    int wv   = tid >> 6;
    int lane = tid & 63;
    const float* C = cost + (size_t)b * NTGT * NSP;
    __shared__ int   way[LDSN];     // pred chain; reused as claim[] first
    __shared__ int   pcol[LDSN];    // col -> assigned row
    __shared__ float uu[LDSN];      // col -> u of its assigned row
    __shared__ float vsh[LDSN];     // column duals v (<= 0)
    __shared__ float urow[NTGT];    // row dual u
    __shared__ int   done[NTGT];    // currently assigned?
    __shared__ float bm1[NTGT];     // stored bid: best reduced cost at scan
    __shared__ float bm2[NTGT];     //             second-best (lower bound)
    __shared__ int   bj [NTGT];     //             best column
    __shared__ float bv [NTGT];     //             v[bj] at scan time
    __shared__ int   qbuf[1024];    // ring buffer of free rows
    __shared__ int   qstate[2];     // qh, qt
    __shared__ int   srow[NWAVES];

    for (int t = tid; t < LDSN; t += 512) {
        pcol[t] = -1; uu[t] = 0.f; vsh[t] = 0.f; way[t] = 0x7fffffff;
    }
    // exact top-2 merge of the 16 per-chunk partials (same tie-break order)
    for (int t = tid; t < NTGT; t += 512) {
        int base16 = (b * NTGT + t) * NCHK;
        float m1 = pm1[base16], m2 = pm2[base16];
        int   mi = pmi[base16];
        #pragma unroll
        for (int k = 1; k < NCHK; ++k) {
            float om1 = pm1[base16 + k], om2 = pm2[base16 + k];
            int   oi  = pmi[base16 + k];
            bool take = (om1 < m1) || (om1 == m1 && oi < mi);
            float lose = take ? m1 : om1;
            m1 = take ? om1 : m1;
            mi = take ? oi  : mi;
            m2 = fminf(fminf(m2, om2), lose);
        }
        urow[t] = m1;
        bm1[t]  = m1;
        bm2[t]  = m2;
        bj[t]   = mi;
        bv[t]   = 0.f;
    }
    if (tid == 0) { qstate[0] = 0; qstate[1] = 0; }
    __syncthreads();

    // ---- Phase A: claim argmin columns (lowest row index wins)
    for (int r = tid; r < NTGT; r += 512) atomicMin(&way[PAD_IDX(bj[r])], r);
    __syncthreads();
    for (int r = tid; r < NTGT; r += 512) {
        int j = bj[r];
        int w = (way[PAD_IDX(j)] == r) ? 1 : 0;
        done[r] = w;
        if (w) { pcol[PAD_IDX(j)] = r; uu[PAD_IDX(j)] = urow[r]; }
    }
    __syncthreads();

    // ---- queue build: wave 0 ballot compaction of Phase-A losers
    if (tid < 64) {
        int qt = 0;
        #pragma unroll
        for (int r0 = 0; r0 < 128; r0 += 64) {
            int r = r0 + lane;
            bool act = (r < NTGT) && !done[r];
            unsigned long long mask = __ballot(act);
            if (act) qbuf[qt + __popcll(mask & ((1ull << lane) - 1ull))] = r;
            qt += __popcll(mask);
        }
        if (lane == 0) qstate[1] = qt;
    }
    __syncthreads();

    int base = lane * 16;

    // ---- Phase B: rounds of (repair-check / rescan) + serial commit
    for (int round = 0; round < ROUND_CAP; ++round) {
        int qh = qstate[0], qt = qstate[1];   // uniform after barrier
        int navail = qt - qh;
        if (navail <= 0) break;
        int take = navail < NWAVES ? navail : NWAVES;
        if (wv < take) {
            int i = qbuf[(qh + wv) & 1023];   // wave-uniform
            if (lane == 0) srow[wv] = i;
            // repairable? exact current reduced cost at stored best column
            float m1p = bm1[i] + (bv[i] - vsh[PAD_IDX(bj[i])]);
            if (m1p > bm2[i]) {
                // full rescan against current prices; store fresh bid
                const float4* row4 = reinterpret_cast<const float4*>(C + (size_t)i * NSP + base);
                float m1 = 1e38f, m2 = 1e38f; int j1 = 0x7fffffff;
                #pragma unroll
                for (int q = 0; q < 4; ++q) {
                    float4 c4 = row4[q];
                    float vals[4];
                    vals[0] = c4.x - vsh[PAD_IDX(base + 4*q + 0)];
                    vals[1] = c4.y - vsh[PAD_IDX(base + 4*q + 1)];
                    vals[2] = c4.z - vsh[PAD_IDX(base + 4*q + 2)];
                    vals[3] = c4.w - vsh[PAD_IDX(base + 4*q + 3)];
                    #pragma unroll
                    for (int e = 0; e < 4; ++e) {
                        float val = vals[e];
                        if (val < m1) { m2 = m1; m1 = val; j1 = base + 4*q + e; }
                        else m2 = fminf(m2, val);
                    }
                }
                #pragma unroll
                for (int off = 32; off >= 1; off >>= 1) {
                    float om1 = __shfl_xor(m1, off);
                    float om2 = __shfl_xor(m2, off);
                    int   oj1 = __shfl_xor(j1, off);
                    bool tk = (om1 < m1) || (om1 == m1 && oj1 < j1);
                    float lose = tk ? m1 : om1;
                    m1 = tk ? om1 : m1;
                    j1 = tk ? oj1 : j1;
                    m2 = fminf(fminf(m2, om2), lose);
                }
                if (lane == 0) {
                    bm1[i] = m1; bm2[i] = m2; bj[i] = j1;
                    bv[i]  = vsh[PAD_IDX(j1)];
                }
            }
        }
        __syncthreads();
        if (tid == 0) {
            int qt2 = qstate[1];
            for (int s = 0; s < take; ++s) {
                int i  = srow[s];
                int j1 = bj[i];
                int pj1 = PAD_IDX(j1);
                float vnow = vsh[pj1];
                float m1p  = bm1[i] + (bv[i] - vnow);   // exact current rc at j1
                if (m1p <= bm2[i]) {
                    float delta = fmaxf(bm2[i] - m1p, AUCTION_EPS);
                    int old = pcol[pj1];
                    vsh[pj1]  = vnow - delta;
                    pcol[pj1] = i;
                    uu[pj1]   = m1p + delta;            // matched edge tight
                    urow[i]   = m1p + delta;
                    done[i]   = 1;
                    if (old >= 0) { qbuf[qt2 & 1023] = old; ++qt2; done[old] = 0; }
                } else {
                    qbuf[qt2 & 1023] = i; ++qt2;        // rescan next round
                }
            }
            qstate[0] = qstate[0] + take;
            qstate[1] = qt2;
        }
        __syncthreads();
    }

    // ---- Phase C: exact shortest augmenting path for leftovers (wave 0)
    float v[16], d[16];
    if (tid < 64) {
        #pragma unroll
        for (int k = 0; k < 16; ++k) v[k] = vsh[PAD_IDX(base + k)];
    }
    __syncthreads();

    for (int i = 0; i < NTGT; ++i) {
        if (done[i]) continue;                 // uniform LDS read
        float ui = urow[i];
        float Df = 0.f;
        int jf = -1;
        if (tid < 64) {
            const float4* row4 = reinterpret_cast<const float4*>(C + (size_t)i * NSP + base);
            #pragma unroll
            for (int q = 0; q < 4; ++q) {
                float4 c4 = row4[q];
                d[4*q+0] = c4.x - ui - v[4*q+0];
                d[4*q+1] = c4.y - ui - v[4*q+1];
                d[4*q+2] = c4.z - ui - v[4*q+2];
                d[4*q+3] = c4.w - ui - v[4*q+3];
            }
            #pragma unroll
            for (int k = 0; k < 16; ++k) way[PAD_IDX(base + k)] = -1;
            unsigned int used = 0;
            int   pf_j = -1;                    // prefetched column (owner row data)
            float pfr[16];

            for (int it = 0; it < NTGT + 3; ++it) {
                // per-lane top-2 (value,index)
                float l1 = 1e38f, l2 = 1e38f;
                int   i1 = 0x7fffffff, i2 = 0x7fffffff;
                #pragma unroll
                for (int k = 0; k < 16; ++k) {
                    float val = ((used >> k) & 1u) ? 1e38f : d[k];
                    int idx = base + k;
                    if (val < l1) { l2 = l1; i2 = i1; l1 = val; i1 = idx; }
                    else if (val < l2) { l2 = val; i2 = idx; }
                }
                // index-carrying top-2 butterfly (no ballot needed)
                #pragma unroll
                for (int off = 32; off >= 1; off >>= 1) {
                    float ob1 = __shfl_xor(l1, off), ob2 = __shfl_xor(l2, off);
                    int   oc1 = __shfl_xor(i1, off), oc2 = __shfl_xor(i2, off);
                    bool tk = (ob1 < l1) || (ob1 == l1 && oc1 < i1);
                    float n1 = tk ? ob1 : l1; int ni1 = tk ? oc1 : i1;
                    float lz = tk ? l1  : ob1; int liz = tk ? i1  : oc1; // loser
                    float n2 = lz; int ni2 = liz;
                    if (l2  < n2) { n2 = l2;  ni2 = i2;  }
                    if (ob2 < n2) { n2 = ob2; ni2 = oc2; }
                    l1 = n1; i1 = ni1; l2 = n2; i2 = ni2;
                }
                float wmin = l1; int j0 = i1; int j0b = i2;
                if (wmin >= 1e37f) break;             // safety net
                int pj0 = pcol[PAD_IDX(j0)];
                if (pj0 < 0) { Df = wmin; jf = j0; break; }   // free column
                if ((j0 >> 4) == lane) used |= 1u << (j0 & 15);
                float uref = uu[PAD_IDX(j0)];
                float sft  = wmin - uref;
                // obtain row pj0 (reuse prefetch on hit)
                float cr[16];
                if (pf_j == j0) {
                    #pragma unroll
                    for (int k = 0; k < 16; ++k) cr[k] = pfr[k];
                    pf_j = -1;
                } else {
                    const float4* rr = reinterpret_cast<const float4*>(C + (size_t)pj0 * NSP + base);
                    #pragma unroll
                    for (int q = 0; q < 4; ++q) {
                        float4 c4 = rr[q];
                        cr[4*q+0] = c4.x; cr[4*q+1] = c4.y; cr[4*q+2] = c4.z; cr[4*q+3] = c4.w;
                    }
                }
                // speculative prefetch: runner-up column's owner row
                if (j0b < NSP && j0b != pf_j) {
                    int pj0b = pcol[PAD_IDX(j0b)];
                    if (pj0b >= 0) {
                        const float4* rb = reinterpret_cast<const float4*>(C + (size_t)pj0b * NSP + base);
                        #pragma unroll
                        for (int q = 0; q < 4; ++q) {
                            float4 c4 = rb[q];
                            pfr[4*q+0] = c4.x; pfr[4*q+1] = c4.y;
                            pfr[4*q+2] = c4.z; pfr[4*q+3] = c4.w;
                        }
                        pf_j = j0b;
                    } else pf_j = -1;
                }
                // relax
                #pragma unroll
                for (int k = 0; k < 16; ++k) {
                    float cand = sft + cr[k] - v[k];
                    bool upd = (cand < d[k]) && !((used >> k) & 1u);
                    if (upd) { d[k] = cand; way[PAD_IDX(base + k)] = j0; }
                }
            }

            // dual updates: v -= (Df - d), u[row] += (Df - d) on scanned cols
            if (jf >= 0) {
                #pragma unroll
                for (int k = 0; k < 16; ++k) {
                    if ((used >> k) & 1u) {
                        float diff = Df - d[k];
                        v[k] -= diff;
                        uu[PAD_IDX(base + k)] += diff;
                    }
                }
            }
        }
        __syncthreads();
        if (tid == 0 && jf >= 0) {            // tid 0 is lane 0 of wave 0
            int j = jf;
            for (int g = 0; g < NSP; ++g) {
                int jp = way[PAD_IDX(j)];
                if (jp < 0) { pcol[PAD_IDX(j)] = i; uu[PAD_IDX(j)] = ui + Df; break; }
                pcol[PAD_IDX(j)] = pcol[PAD_IDX(jp)];
                uu[PAD_IDX(j)]   = uu[PAD_IDX(jp)];
                j = jp;
            }
            done[i] = 1;
        }
        __syncthreads();
    }

    // ---- mean of matched costs (wave 0)
    if (tid < 64) {
        float acc = 0.f;
        #pragma unroll
        for (int k = 0; k < 16; ++k) {
            int j = base + k;
            if (j < NSRC) {
                int r = pcol[PAD_IDX(j)];
                if (r >= 0) acc += C[(size_t)r * NSP + j];
            }
        }
        #pragma unroll
        for (int off = 32; off >= 1; off >>= 1) acc += __shfl_xor(acc, off);
        if (lane == 0) out[b] = acc * (1.0f / NTGT);
    }
}

extern "C" void kernel_launch(void* const* d_in, const int* in_sizes, int n_in,
                              void* d_out, int out_size, void* d_ws, size_t ws_size,
                              hipStream_t stream) {
    const float* logits = (const float*)d_in[0];   // (32,1000,256) f32
    const int*   tcls   = (const int*)  d_in[1];   // (32,100) i32
    const float* sbox   = (const float*)d_in[2];   // (32,1000,4) f32
    const float* tbox   = (const float*)d_in[3];   // (32,100,4) f32
    float* out = (float*)d_out;                    // (32,) f32

    float* cost = (float*)d_ws;                            // 32*100*1024 floats (~13.1 MB)
    float* pm1  = cost + (size_t)NB * NTGT * NSP;          // 3200*16 floats
    float* pm2  = pm1 + (size_t)NB * NTGT * NCHK;          // 3200*16 floats
    int*   pmi  = (int*)(pm2 + (size_t)NB * NTGT * NCHK);  // 3200*16 ints

    cost_kernel<<<NB * NCHK, 512, 0, stream>>>(logits, tcls, sbox, tbox, cost,
                                               pm1, pm2, pmi);
    lsa_kernel <<<NB,        512, 0, stream>>>(cost, pm1, pm2, pmi, out);
}